// Round 4
// baseline (4525.658 us; speedup 1.0000x reference)
//
#include <hip/hip_runtime.h>

#define N_VOX 200000
#define K_OFF 27
#define P_PAIR 400000
#define C_IN 32
#define C_MID 64
#define C_OUT 32
#define VT 256                                  // output voxels per tile
#define NTILES ((N_VOX + VT - 1) / VT)          // 782
#define NBUCK (K_OFF * NTILES)                  // 21114
#define NPAIR_TOT (K_OFF * P_PAIR)              // 10,800,000

typedef __attribute__((ext_vector_type(8))) short short8;
typedef __attribute__((ext_vector_type(4))) float f32x4;

__device__ inline short f2bf(float f) {
    union { float f; unsigned u; } v; v.f = f;
    unsigned r = v.u + 0x7FFF + ((v.u >> 16) & 1);   // round-to-nearest-even
    return (short)(r >> 16);
}

// ---------------- CSR build: bucket valid pairs by (k, out-voxel-tile) -----

__global__ __launch_bounds__(256) void count_kernel(
    const int* __restrict__ out_idx, const float* __restrict__ mask,
    int* __restrict__ counts)
{
    const int e = blockIdx.x * 256 + threadIdx.x;
    if (e >= NPAIR_TOT) return;
    if (mask[e] > 0.5f) {
        const int k = e / P_PAIR;                    // const-div -> magic mul
        const int b = k * NTILES + (out_idx[e] >> 8);
        atomicAdd(&counts[b], 1);
    }
}

__global__ __launch_bounds__(256) void scan_kernel(
    const int* __restrict__ counts, int* __restrict__ offsets,
    int* __restrict__ cursor)
{
    __shared__ int part[256];
    const int CH = (NBUCK + 255) / 256;              // 83
    const int t = threadIdx.x;
    int s = 0;
    for (int j = 0; j < CH; ++j) { const int i = t * CH + j; if (i < NBUCK) s += counts[i]; }
    part[t] = s;
    __syncthreads();
    if (t == 0) {
        int run = 0;
        for (int i = 0; i < 256; ++i) { const int tmp = part[i]; part[i] = run; run += tmp; }
    }
    __syncthreads();
    int run = part[t];
    for (int j = 0; j < CH; ++j) {
        const int i = t * CH + j;
        if (i < NBUCK) { offsets[i] = run; cursor[i] = run; run += counts[i]; }
    }
}

// eids[pos] = in_idx | (local_out << 18); in_idx < 200000 < 2^18, local < 256.
__global__ __launch_bounds__(256) void fill_kernel(
    const int* __restrict__ in_idx, const int* __restrict__ out_idx,
    const float* __restrict__ mask, int* __restrict__ cursor,
    int* __restrict__ eids)
{
    const int e = blockIdx.x * 256 + threadIdx.x;
    if (e >= NPAIR_TOT) return;
    if (mask[e] > 0.5f) {
        const int k = e / P_PAIR;
        const int v = out_idx[e];
        const int b = k * NTILES + (v >> 8);
        const int pos = atomicAdd(&cursor[b], 1);
        eids[pos] = in_idx[e] | ((v & 255) << 18);
    }
}

// ---------------- conv1: output-stationary, LDS accumulator ----------------
// Per block: one 256-voxel tile; loop k=0..26 over this tile's buckets.
// MFMA 16x16x32 bf16 (R3-proven fragments): A-row r = entry base+r,
// lane k-chunk g*8..+7; C/D row m=4g+i, col r. Scatter -> LDS atomics.
__global__ __launch_bounds__(256) void conv1_tile(
    const float* __restrict__ feats, const float* __restrict__ W_in,
    const int* __restrict__ eids, const int* __restrict__ offsets,
    const int* __restrict__ counts, float* __restrict__ h)
{
    __shared__ float hs[VT * C_MID];                 // 64 KB
    const int tile = blockIdx.x;
    const int tid  = threadIdx.x;
    for (int t = tid; t < VT * C_MID; t += 256) hs[t] = 0.f;
    __syncthreads();

    const int lane = tid & 63, wave = tid >> 6;
    const int g = lane >> 4, r = lane & 15;

    for (int k = 0; k < K_OFF; ++k) {
        const int bk    = k * NTILES + tile;
        const int start = offsets[bk];
        const int cnt   = counts[bk];
        if (cnt == 0) continue;

        const float* Wk = W_in + (size_t)k * (C_IN * C_MID);
        short8 bfrag[4];
#pragma unroll
        for (int nt = 0; nt < 4; ++nt) {
            short8 b;
#pragma unroll
            for (int j = 0; j < 8; ++j)
                b[j] = f2bf(Wk[(g * 8 + j) * C_MID + nt * 16 + r]);
            bfrag[nt] = b;
        }

        for (int base = wave * 16; base < cnt; base += 64) {
            short8 a = {};
            if (base + r < cnt) {
                const int eid = eids[start + base + r];
                const int vin = eid & 0x3FFFF;
                const f32x4* src = (const f32x4*)(feats + (size_t)vin * C_IN + g * 8);
                f32x4 x0 = src[0], x1 = src[1];
#pragma unroll
                for (int j = 0; j < 4; ++j) { a[j] = f2bf(x0[j]); a[4 + j] = f2bf(x1[j]); }
            }

            f32x4 acc0 = {}, acc1 = {}, acc2 = {}, acc3 = {};
            acc0 = __builtin_amdgcn_mfma_f32_16x16x32_bf16(a, bfrag[0], acc0, 0, 0, 0);
            acc1 = __builtin_amdgcn_mfma_f32_16x16x32_bf16(a, bfrag[1], acc1, 0, 0, 0);
            acc2 = __builtin_amdgcn_mfma_f32_16x16x32_bf16(a, bfrag[2], acc2, 0, 0, 0);
            acc3 = __builtin_amdgcn_mfma_f32_16x16x32_bf16(a, bfrag[3], acc3, 0, 0, 0);

#pragma unroll
            for (int i = 0; i < 4; ++i) {
                const int m = g * 4 + i;
                if (base + m < cnt) {
                    const int eid = eids[start + base + m];    // broadcast load
                    const int local = eid >> 18;
                    float* hp = &hs[local * C_MID + r];
                    atomicAdd(hp +  0, acc0[i]);
                    atomicAdd(hp + 16, acc1[i]);
                    atomicAdd(hp + 32, acc2[i]);
                    atomicAdd(hp + 48, acc3[i]);
                }
            }
        }
    }
    __syncthreads();

    const int vbase = tile * VT;
    for (int t = tid; t < VT * C_MID; t += 256) {
        const int v = vbase + (t >> 6);
        if (v < N_VOX) h[(size_t)v * C_MID + (t & 63)] = hs[t];
    }
}

// ---------------- conv2: same structure, K=64 (2 k-steps), N=32 ------------
__global__ __launch_bounds__(256) void conv2_tile(
    const float* __restrict__ h, const float* __restrict__ W_out,
    const int* __restrict__ eids, const int* __restrict__ offsets,
    const int* __restrict__ counts, float* __restrict__ out)
{
    __shared__ float os[VT * C_OUT];                 // 32 KB
    const int tile = blockIdx.x;
    const int tid  = threadIdx.x;
    for (int t = tid; t < VT * C_OUT; t += 256) os[t] = 0.f;
    __syncthreads();

    const int lane = tid & 63, wave = tid >> 6;
    const int g = lane >> 4, r = lane & 15;

    for (int k = 0; k < K_OFF; ++k) {
        const int bk    = k * NTILES + tile;
        const int start = offsets[bk];
        const int cnt   = counts[bk];
        if (cnt == 0) continue;

        const float* Wk = W_out + (size_t)k * (C_MID * C_OUT);
        short8 bfrag[2][2];                          // [n-tile][k-step]
#pragma unroll
        for (int nt = 0; nt < 2; ++nt)
#pragma unroll
            for (int ks = 0; ks < 2; ++ks) {
                short8 b;
#pragma unroll
                for (int j = 0; j < 8; ++j)
                    b[j] = f2bf(Wk[(ks * 32 + g * 8 + j) * C_OUT + nt * 16 + r]);
                bfrag[nt][ks] = b;
            }

        for (int base = wave * 16; base < cnt; base += 64) {
            short8 a0 = {}, a1 = {};
            if (base + r < cnt) {
                const int eid = eids[start + base + r];
                const int vin = eid & 0x3FFFF;
                const f32x4* src = (const f32x4*)(h + (size_t)vin * C_MID + g * 8);
                f32x4 x0 = src[0], x1 = src[1];      // k-step 0: ch g*8..+7
                f32x4 y0 = src[8], y1 = src[9];      // k-step 1: ch 32+g*8..
#pragma unroll
                for (int j = 0; j < 4; ++j) {
                    a0[j]     = f2bf(fmaxf(x0[j], 0.f));
                    a0[4 + j] = f2bf(fmaxf(x1[j], 0.f));
                    a1[j]     = f2bf(fmaxf(y0[j], 0.f));
                    a1[4 + j] = f2bf(fmaxf(y1[j], 0.f));
                }
            }

            f32x4 acc0 = {}, acc1 = {};
            acc0 = __builtin_amdgcn_mfma_f32_16x16x32_bf16(a0, bfrag[0][0], acc0, 0, 0, 0);
            acc0 = __builtin_amdgcn_mfma_f32_16x16x32_bf16(a1, bfrag[0][1], acc0, 0, 0, 0);
            acc1 = __builtin_amdgcn_mfma_f32_16x16x32_bf16(a0, bfrag[1][0], acc1, 0, 0, 0);
            acc1 = __builtin_amdgcn_mfma_f32_16x16x32_bf16(a1, bfrag[1][1], acc1, 0, 0, 0);

#pragma unroll
            for (int i = 0; i < 4; ++i) {
                const int m = g * 4 + i;
                if (base + m < cnt) {
                    const int eid = eids[start + base + m];
                    const int local = eid >> 18;
                    float* op = &os[local * C_OUT + r];
                    atomicAdd(op +  0, acc0[i]);
                    atomicAdd(op + 16, acc1[i]);
                }
            }
        }
    }
    __syncthreads();

    const int vbase = tile * VT;
    for (int t = tid; t < VT * C_OUT; t += 256) {
        const int v = vbase + (t >> 5);
        if (v < N_VOX) out[(size_t)v * C_OUT + (t & 31)] = os[t];
    }
}

// ---------------------------------------------------------------------------

extern "C" void kernel_launch(void* const* d_in, const int* in_sizes, int n_in,
                              void* d_out, int out_size, void* d_ws, size_t ws_size,
                              hipStream_t stream) {
    const float* feats   = (const float*)d_in[0];
    const int*   in_idx  = (const int*)  d_in[1];
    const int*   out_idx = (const int*)  d_in[2];
    const float* mask    = (const float*)d_in[3];
    const float* W_in    = (const float*)d_in[4];
    const float* W_out   = (const float*)d_in[5];
    float* out = (float*)d_out;

    // ws layout (bytes): h | eids(worst-case all-valid) | counts | offsets | cursor
    char* ws = (char*)d_ws;
    float* h       = (float*)(ws);                              // 51,200,000
    int*   eids    = (int*)  (ws + 51200000);                   // 43,200,000
    int*   counts  = (int*)  (ws + 94400000);                   //     84,456 -> pad 84,480
    int*   offsets = (int*)  (ws + 94484480);
    int*   cursor  = (int*)  (ws + 94568960);                   // end ~94.65 MB

    hipMemsetAsync(counts, 0, NBUCK * sizeof(int), stream);

    const int nblk = (NPAIR_TOT + 255) / 256;
    count_kernel<<<nblk, 256, 0, stream>>>(out_idx, mask, counts);
    scan_kernel <<<1,    256, 0, stream>>>(counts, offsets, cursor);
    fill_kernel <<<nblk, 256, 0, stream>>>(in_idx, out_idx, mask, cursor, eids);

    conv1_tile<<<NTILES, 256, 0, stream>>>(feats, W_in, eids, offsets, counts, h);
    conv2_tile<<<NTILES, 256, 0, stream>>>(h, W_out, eids, offsets, counts, out);
}

// Round 5
// 3671.489 us; speedup vs baseline: 1.2326x; 1.2326x over previous
//
#include <hip/hip_runtime.h>

#define N_VOX 200000
#define K_OFF 27
#define P_PAIR 400000
#define C_IN 32
#define C_MID 64
#define C_OUT 32
#define VT 16                                   // voxels per wave-owned group
#define NT16 (N_VOX / VT)                       // 12500 (exact)
#define NBUCK (K_OFF * NT16)                    // 337500
#define NPAIR_TOT (K_OFF * P_PAIR)              // 10,800,000
#define SCAN_CH ((NBUCK + 255) / 256)           // 1319

typedef __attribute__((ext_vector_type(8))) short short8;
typedef __attribute__((ext_vector_type(4))) float f32x4;

__device__ inline short f2bf(float f) {
    union { float f; unsigned u; } v; v.f = f;
    unsigned r = v.u + 0x7FFF + ((v.u >> 16) & 1);   // round-to-nearest-even
    return (short)(r >> 16);
}

// ---------------- feats f32 -> bf16 (12.8 MB table, halves gather bytes) ---
__global__ __launch_bounds__(256) void cvt_feats(
    const float* __restrict__ in, unsigned short* __restrict__ out)
{
    const int i = blockIdx.x * 256 + threadIdx.x;    // 4 elements each
    if (i * 4 >= N_VOX * C_IN) return;
    f32x4 v = ((const f32x4*)in)[i];
    unsigned int w0 = (unsigned short)f2bf(v[0]) | ((unsigned)(unsigned short)f2bf(v[1]) << 16);
    unsigned int w1 = (unsigned short)f2bf(v[2]) | ((unsigned)(unsigned short)f2bf(v[3]) << 16);
    ((unsigned int*)out)[2 * i]     = w0;
    ((unsigned int*)out)[2 * i + 1] = w1;
}

// ---------------- CSR build: bucket valid pairs by (k, 16-voxel group) -----
__global__ __launch_bounds__(256) void count_kernel(
    const int* __restrict__ out_idx, const float* __restrict__ mask,
    int* __restrict__ counts)
{
    const int e = blockIdx.x * 256 + threadIdx.x;
    if (e >= NPAIR_TOT) return;
    if (mask[e] > 0.5f) {
        const int k = e / P_PAIR;
        const int b = k * NT16 + (out_idx[e] >> 4);
        atomicAdd(&counts[b], 1);
    }
}

// Transposed-chain scan: thread t owns buckets {j*256+t} (coalesced loads);
// each chain gets a contiguous storage range. Bucket order in eids is
// irrelevant — conv kernels address via offsets[].
__global__ __launch_bounds__(256) void scan_kernel(
    const int* __restrict__ counts, int* __restrict__ offsets,
    int* __restrict__ cursor)
{
    __shared__ int part[256];
    const int t = threadIdx.x;
    int s = 0;
    for (int j = 0; j < SCAN_CH; ++j) {
        const int i = j * 256 + t;
        if (i < NBUCK) s += counts[i];
    }
    part[t] = s;
    __syncthreads();
    if (t == 0) {
        int run = 0;
        for (int i = 0; i < 256; ++i) { const int tmp = part[i]; part[i] = run; run += tmp; }
    }
    __syncthreads();
    int run = part[t];
    for (int j = 0; j < SCAN_CH; ++j) {
        const int i = j * 256 + t;
        if (i < NBUCK) { offsets[i] = run; cursor[i] = run; run += counts[i]; }
    }
}

// eids[pos] = in_idx | (local_out << 18); in_idx < 2^18, local < 16.
__global__ __launch_bounds__(256) void fill_kernel(
    const int* __restrict__ in_idx, const int* __restrict__ out_idx,
    const float* __restrict__ mask, int* __restrict__ cursor,
    int* __restrict__ eids)
{
    const int e = blockIdx.x * 256 + threadIdx.x;
    if (e >= NPAIR_TOT) return;
    if (mask[e] > 0.5f) {
        const int k = e / P_PAIR;
        const int v = out_idx[e];
        const int b = k * NT16 + (v >> 4);
        const int pos = atomicAdd(&cursor[b], 1);
        eids[pos] = in_idx[e] | ((v & 15) << 18);
    }
}

// ---------------- conv1: wave-private 16-voxel LDS accumulator -------------
// Wave owns voxel group b16 (= blockIdx.x*4 + wave); loops k, one ~16-entry
// MFMA tile per bucket. R3-proven fragments; scatter -> wave-private LDS
// atomics; h written once, ReLU'd, bf16, fully coalesced. No __syncthreads.
__global__ __launch_bounds__(256) void conv1_tile(
    const unsigned short* __restrict__ featsb, const float* __restrict__ W_in,
    const int* __restrict__ eids, const int* __restrict__ offsets,
    const int* __restrict__ counts, unsigned short* __restrict__ h)
{
    __shared__ float hs[4][VT * C_MID];              // 4 waves x 4 KB = 16 KB
    const int tid = threadIdx.x, lane = tid & 63, wave = tid >> 6;
    const int g = lane >> 4, r = lane & 15;
    const int b16 = blockIdx.x * 4 + wave;
    float* hw = hs[wave];
    for (int i = lane; i < VT * C_MID; i += 64) hw[i] = 0.f;

    for (int k = 0; k < K_OFF; ++k) {
        const int bk    = k * NT16 + b16;
        const int start = offsets[bk];
        const int cnt   = counts[bk];
        if (cnt == 0) continue;

        const float* Wk = W_in + (size_t)k * (C_IN * C_MID);
        short8 bfrag[4];
#pragma unroll
        for (int nt = 0; nt < 4; ++nt) {
            short8 b;
#pragma unroll
            for (int j = 0; j < 8; ++j)
                b[j] = f2bf(Wk[(g * 8 + j) * C_MID + nt * 16 + r]);
            bfrag[nt] = b;
        }

        for (int base = 0; base < cnt; base += 16) {
            short8 a = {};
            if (base + r < cnt) {
                const int vin = eids[start + base + r] & 0x3FFFF;
                a = *(const short8*)(featsb + (size_t)vin * C_IN + g * 8);
            }

            f32x4 acc0 = {}, acc1 = {}, acc2 = {}, acc3 = {};
            acc0 = __builtin_amdgcn_mfma_f32_16x16x32_bf16(a, bfrag[0], acc0, 0, 0, 0);
            acc1 = __builtin_amdgcn_mfma_f32_16x16x32_bf16(a, bfrag[1], acc1, 0, 0, 0);
            acc2 = __builtin_amdgcn_mfma_f32_16x16x32_bf16(a, bfrag[2], acc2, 0, 0, 0);
            acc3 = __builtin_amdgcn_mfma_f32_16x16x32_bf16(a, bfrag[3], acc3, 0, 0, 0);

#pragma unroll
            for (int i = 0; i < 4; ++i) {
                const int m = g * 4 + i;
                if (base + m < cnt) {
                    const int local = eids[start + base + m] >> 18;  // L1-hot
                    float* hp = &hw[local * C_MID + r];
                    atomicAdd(hp +  0, acc0[i]);
                    atomicAdd(hp + 16, acc1[i]);
                    atomicAdd(hp + 32, acc2[i]);
                    atomicAdd(hp + 48, acc3[i]);
                }
            }
        }
    }

    // h rows b16*16 .. +15: ReLU + bf16, packed 2/write, coalesced.
    unsigned int* hout = (unsigned int*)(h + (size_t)b16 * VT * C_MID);
    for (int i = lane; i < VT * C_MID / 2; i += 64) {
        const unsigned short lo = (unsigned short)f2bf(fmaxf(hw[2 * i],     0.f));
        const unsigned short hi = (unsigned short)f2bf(fmaxf(hw[2 * i + 1], 0.f));
        hout[i] = (unsigned)lo | ((unsigned)hi << 16);
    }
}

// ---------------- conv2: same structure, bf16 h (ReLU pre-applied) ---------
__global__ __launch_bounds__(256) void conv2_tile(
    const unsigned short* __restrict__ h, const float* __restrict__ W_out,
    const int* __restrict__ eids, const int* __restrict__ offsets,
    const int* __restrict__ counts, float* __restrict__ out)
{
    __shared__ float os[4][VT * C_OUT];              // 4 x 2 KB = 8 KB
    const int tid = threadIdx.x, lane = tid & 63, wave = tid >> 6;
    const int g = lane >> 4, r = lane & 15;
    const int b16 = blockIdx.x * 4 + wave;
    float* ow = os[wave];
    for (int i = lane; i < VT * C_OUT; i += 64) ow[i] = 0.f;

    for (int k = 0; k < K_OFF; ++k) {
        const int bk    = k * NT16 + b16;
        const int start = offsets[bk];
        const int cnt   = counts[bk];
        if (cnt == 0) continue;

        const float* Wk = W_out + (size_t)k * (C_MID * C_OUT);
        short8 bfrag[2][2];                          // [n-tile][k-step]
#pragma unroll
        for (int nt = 0; nt < 2; ++nt)
#pragma unroll
            for (int ks = 0; ks < 2; ++ks) {
                short8 b;
#pragma unroll
                for (int j = 0; j < 8; ++j)
                    b[j] = f2bf(Wk[(ks * 32 + g * 8 + j) * C_OUT + nt * 16 + r]);
                bfrag[nt][ks] = b;
            }

        for (int base = 0; base < cnt; base += 16) {
            short8 a0 = {}, a1 = {};
            if (base + r < cnt) {
                const int vin = eids[start + base + r] & 0x3FFFF;
                const short8* row = (const short8*)(h + (size_t)vin * C_MID);
                a0 = row[g];                         // ch g*8..+7   (k-step 0)
                a1 = row[4 + g];                     // ch 32+g*8..  (k-step 1)
            }

            f32x4 acc0 = {}, acc1 = {};
            acc0 = __builtin_amdgcn_mfma_f32_16x16x32_bf16(a0, bfrag[0][0], acc0, 0, 0, 0);
            acc0 = __builtin_amdgcn_mfma_f32_16x16x32_bf16(a1, bfrag[0][1], acc0, 0, 0, 0);
            acc1 = __builtin_amdgcn_mfma_f32_16x16x32_bf16(a0, bfrag[1][0], acc1, 0, 0, 0);
            acc1 = __builtin_amdgcn_mfma_f32_16x16x32_bf16(a1, bfrag[1][1], acc1, 0, 0, 0);

#pragma unroll
            for (int i = 0; i < 4; ++i) {
                const int m = g * 4 + i;
                if (base + m < cnt) {
                    const int local = eids[start + base + m] >> 18;
                    float* op = &ow[local * C_OUT + r];
                    atomicAdd(op +  0, acc0[i]);
                    atomicAdd(op + 16, acc1[i]);
                }
            }
        }
    }

    float* optr = out + (size_t)b16 * VT * C_OUT;
    for (int i = lane; i < VT * C_OUT; i += 64) optr[i] = ow[i];
}

// ---------------------------------------------------------------------------
extern "C" void kernel_launch(void* const* d_in, const int* in_sizes, int n_in,
                              void* d_out, int out_size, void* d_ws, size_t ws_size,
                              hipStream_t stream) {
    const float* feats   = (const float*)d_in[0];
    const int*   in_idx  = (const int*)  d_in[1];
    const int*   out_idx = (const int*)  d_in[2];
    const float* mask    = (const float*)d_in[3];
    const float* W_in    = (const float*)d_in[4];
    const float* W_out   = (const float*)d_in[5];
    float* out = (float*)d_out;

    // ws layout (bytes): h_bf16 | feats_bf16 | eids | counts | offsets | cursor
    char* ws = (char*)d_ws;
    unsigned short* h      = (unsigned short*)(ws);              // 25,600,000
    unsigned short* featsb = (unsigned short*)(ws + 25600000);   // 12,800,000
    int* eids    = (int*)(ws + 38400000);                        // 43,200,000
    int* counts  = (int*)(ws + 81600000);                        //  1,350,000
    int* offsets = (int*)(ws + 82950000);                        //  1,350,000
    int* cursor  = (int*)(ws + 84300000);                        // end ~85.65 MB

    hipMemsetAsync(counts, 0, NBUCK * sizeof(int), stream);

    cvt_feats<<<(N_VOX * C_IN / 4 + 255) / 256, 256, 0, stream>>>(feats, featsb);

    const int nblk = (NPAIR_TOT + 255) / 256;
    count_kernel<<<nblk, 256, 0, stream>>>(out_idx, mask, counts);
    scan_kernel <<<1,    256, 0, stream>>>(counts, offsets, cursor);
    fill_kernel <<<nblk, 256, 0, stream>>>(in_idx, out_idx, mask, cursor, eids);

    conv1_tile<<<NT16 / 4, 256, 0, stream>>>(featsb, W_in, eids, offsets, counts, h);
    conv2_tile<<<NT16 / 4, 256, 0, stream>>>(h, W_out, eids, offsets, counts, out);
}